// Round 1
// baseline (3164.198 us; speedup 1.0000x reference)
//
#include <hip/hip_runtime.h>
#include <cmath>

#define H     4096
#define H3    12288
#define VOCAB 4
#define NSTEPS 48
#define PAD_TOK 3

// ws layout (floats):
//   G  : [52][12288]  rows 0..3 = emb[v]@W_ih^T (no bias), rows 4..51 = pos[t]@W_ih^T + b_ih
//   gh : [12288]
//   h  : [4096]
//   tok: 1 int
// total = (52*12288 + 12288 + 4096)*4 + 4 = ~2.63 MB

__global__ void init_kernel(const float* __restrict__ h0, float* __restrict__ h,
                            int* __restrict__ tok, int* __restrict__ out) {
    int tid = threadIdx.x;
    for (int i = tid; i < H; i += 256) h[i] = h0[i];
    if (tid == 0) {
        *tok = PAD_TOK;
        out[12] = PAD_TOK; out[25] = PAD_TOK; out[38] = PAD_TOK; out[51] = PAD_TOK;
    }
}

// Precompute G = X @ W_ih^T (+ b_ih on pos rows).
// X rows: 0..3 = token_embedding, 4..51 = pos_embedding[0..47].
// Block: 1024 thr = 16 waves; block covers 16 j's; wave w: jset=w&3 (4 j's), rset=w>>2 (13 r's).
__global__ __launch_bounds__(1024)
void precompute_kernel(const float* __restrict__ emb, const float* __restrict__ pos,
                       const float* __restrict__ W_ih, const float* __restrict__ b_ih,
                       float* __restrict__ G) {
    __shared__ float xs[52 * 256];
    const int tid  = threadIdx.x;
    const int wave = tid >> 6;
    const int lane = tid & 63;
    const int jset = wave & 3;
    const int rset = wave >> 2;
    const int j0   = blockIdx.x * 16 + jset * 4;
    const int rbase = rset * 13;

    float acc[4][13];
    #pragma unroll
    for (int a = 0; a < 4; ++a)
        #pragma unroll
        for (int b = 0; b < 13; ++b) acc[a][b] = 0.f;

    for (int c = 0; c < 16; ++c) {
        const int k0 = c * 256;
        __syncthreads();                       // readers of xs (prev chunk) done
        for (int idx = tid; idx < 52 * 256; idx += 1024) {
            int r = idx >> 8, kk = idx & 255;
            xs[idx] = (r < 4) ? emb[r * H + k0 + kk]
                              : pos[(r - 4) * H + k0 + kk];
        }
        __syncthreads();

        float4 w4[4];
        #pragma unroll
        for (int a = 0; a < 4; ++a)
            w4[a] = *(const float4*)(W_ih + (size_t)(j0 + a) * H + k0 + lane * 4);

        #pragma unroll
        for (int b = 0; b < 13; ++b) {
            float4 x4 = *(const float4*)(xs + (rbase + b) * 256 + lane * 4);
            #pragma unroll
            for (int a = 0; a < 4; ++a)
                acc[a][b] += w4[a].x * x4.x + w4[a].y * x4.y
                           + w4[a].z * x4.z + w4[a].w * x4.w;
        }
    }

    #pragma unroll
    for (int b = 0; b < 13; ++b) {
        #pragma unroll
        for (int a = 0; a < 4; ++a) {
            float v = acc[a][b];
            for (int off = 32; off; off >>= 1) v += __shfl_xor(v, off, 64);
            if (lane == 0) {
                int r = rbase + b, j = j0 + a;
                G[(size_t)r * H3 + j] = v + (r >= 4 ? b_ih[j] : 0.f);
            }
        }
    }
}

// gh = W_hh @ h + b_hh.  Grid 768 x 256 thr; block = 16 rows (4 per wave).
__global__ __launch_bounds__(256)
void gh_matvec_kernel(const float* __restrict__ W_hh, const float* __restrict__ b_hh,
                      const float* __restrict__ h, float* __restrict__ gh) {
    __shared__ float4 hs4[1024];
    const int tid = threadIdx.x;
    for (int i = tid; i < 1024; i += 256) hs4[i] = *(const float4*)(h + i * 4);
    __syncthreads();

    const int wave = tid >> 6, lane = tid & 63;
    #pragma unroll 2
    for (int jj = 0; jj < 4; ++jj) {
        const int j = blockIdx.x * 16 + wave * 4 + jj;
        const float* row = W_hh + (size_t)j * H;
        float4 a = {0.f, 0.f, 0.f, 0.f};
        #pragma unroll
        for (int i = 0; i < 16; ++i) {
            float4 w4 = *(const float4*)(row + i * 256 + lane * 4);
            float4 x4 = hs4[i * 64 + lane];
            a.x += w4.x * x4.x; a.y += w4.y * x4.y;
            a.z += w4.z * x4.z; a.w += w4.w * x4.w;
        }
        float s = a.x + a.y + a.z + a.w;
        for (int off = 32; off; off >>= 1) s += __shfl_xor(s, off, 64);
        if (lane == 0) gh[j] = s + b_hh[j];
    }
}

// Single-block: gates + h update + logits + argmax + next-token select.
__global__ __launch_bounds__(1024)
void step_kernel(const float* __restrict__ G, const float* __restrict__ gh,
                 const float* __restrict__ W_out, const float* __restrict__ b_out,
                 float* __restrict__ h, int* __restrict__ tok, int* __restrict__ out,
                 int t) {
    __shared__ float hs[H];
    __shared__ float red[16][4];
    const int tid = threadIdx.x;
    const int tk = *tok;
    const float* gE = G + (size_t)tk * H3;
    const float* gP = G + (size_t)(4 + t) * H3;

    #pragma unroll
    for (int s = 0; s < 4; ++s) {
        int i = tid + s * 1024;
        float gir = gE[i]         + gP[i];
        float giz = gE[H + i]     + gP[H + i];
        float gin = gE[2 * H + i] + gP[2 * H + i];
        float ghr = gh[i], ghz = gh[H + i], ghn = gh[2 * H + i];
        float r = 1.f / (1.f + expf(-(gir + ghr)));
        float z = 1.f / (1.f + expf(-(giz + ghz)));
        float n = tanhf(gin + r * ghn);
        float hn = (1.f - z) * n + z * h[i];
        h[i] = hn;
        hs[i] = hn;
    }
    __syncthreads();

    float p0 = 0.f, p1 = 0.f, p2 = 0.f, p3 = 0.f;
    #pragma unroll
    for (int s = 0; s < 4; ++s) {
        int i = tid + s * 1024;
        float hv = hs[i];
        p0 += W_out[i] * hv;
        p1 += W_out[H + i] * hv;
        p2 += W_out[2 * H + i] * hv;
        p3 += W_out[3 * H + i] * hv;
    }
    for (int off = 32; off; off >>= 1) {
        p0 += __shfl_xor(p0, off, 64); p1 += __shfl_xor(p1, off, 64);
        p2 += __shfl_xor(p2, off, 64); p3 += __shfl_xor(p3, off, 64);
    }
    const int wave = tid >> 6, lane = tid & 63;
    if (lane == 0) { red[wave][0] = p0; red[wave][1] = p1; red[wave][2] = p2; red[wave][3] = p3; }
    __syncthreads();

    if (tid == 0) {
        float lg[4];
        for (int v = 0; v < 4; ++v) {
            float s = b_out[v];
            for (int w = 0; w < 16; ++w) s += red[w][v];
            lg[v] = s;
        }
        int best = 0;
        for (int v = 1; v < 4; ++v) if (lg[v] > lg[best]) best = v;  // first-max tiebreak
        out[(t / 12) * 13 + (t % 12)] = best;
        *tok = ((t + 1) % 12 == 0) ? PAD_TOK : best;
    }
}

extern "C" void kernel_launch(void* const* d_in, const int* in_sizes, int n_in,
                              void* d_out, int out_size, void* d_ws, size_t ws_size,
                              hipStream_t stream) {
    const float* h0    = (const float*)d_in[0];
    const float* emb   = (const float*)d_in[1];
    const float* pos   = (const float*)d_in[2];
    const float* W_ih  = (const float*)d_in[3];
    const float* W_hh  = (const float*)d_in[4];
    const float* b_ih  = (const float*)d_in[5];
    const float* b_hh  = (const float*)d_in[6];
    const float* W_out = (const float*)d_in[7];
    const float* b_out = (const float*)d_in[8];

    int*   out = (int*)d_out;
    float* ws  = (float*)d_ws;
    float* G   = ws;                    // 52*12288
    float* gh  = ws + 52 * H3;          // 12288
    float* h   = gh + H3;               // 4096
    int*   tok = (int*)(h + H);         // 1

    hipLaunchKernelGGL(init_kernel, dim3(1), dim3(256), 0, stream, h0, h, tok, out);
    hipLaunchKernelGGL(precompute_kernel, dim3(768), dim3(1024), 0, stream,
                       emb, pos, W_ih, b_ih, G);
    for (int t = 0; t < NSTEPS; ++t) {
        hipLaunchKernelGGL(gh_matvec_kernel, dim3(768), dim3(256), 0, stream,
                           W_hh, b_hh, h, gh);
        hipLaunchKernelGGL(step_kernel, dim3(1), dim3(1024), 0, stream,
                           G, gh, W_out, b_out, h, tok, out, t);
    }
}

// Round 2
// 1888.037 us; speedup vs baseline: 1.6759x; 1.6759x over previous
//
#include <hip/hip_runtime.h>
#include <cmath>

#define H     4096
#define H3    12288
#define VOCAB 4
#define NSTEPS 48
#define PAD_TOK 3

// ws layout (floats):
//   G       : [52][12288]   rows 0..3 = emb[v]@W_ih^T, rows 4..51 = pos[t]@W_ih^T + b_ih
//   hA, hB  : [4096] each   (double-buffered hidden state)
//   partial : [512][4]      per-block partial logits
//   tok     : 1 int

__global__ void init_kernel(const float* __restrict__ h0, float* __restrict__ hA,
                            int* __restrict__ tok, int* __restrict__ out) {
    int tid = threadIdx.x;
    for (int i = tid; i < H; i += 256) hA[i] = h0[i];
    if (tid == 0) {
        *tok = PAD_TOK;
        out[12] = PAD_TOK; out[25] = PAD_TOK; out[38] = PAD_TOK; out[51] = PAD_TOK;
    }
}

// G = X @ W_ih^T (+ b_ih on pos rows).  X rows: 0..3 = emb, 4..51 = pos[0..47].
// 768 blocks x 512 thr (8 waves). Each wave owns 2 W_ih rows (j0, j0+1) and ALL 52
// X rows: 104 accumulators/lane, k split across lanes (float4), shuffle-reduce at end.
// 512-thr block => VGPR cap 256: no spills (the round-1 bug was a 64-VGPR cap + spills).
__global__ __launch_bounds__(512)
void precompute_kernel(const float* __restrict__ emb, const float* __restrict__ pos,
                       const float* __restrict__ W_ih, const float* __restrict__ b_ih,
                       float* __restrict__ G) {
    __shared__ float xs[52 * 256];            // 53 KB
    const int tid  = threadIdx.x;
    const int wave = tid >> 6;
    const int lane = tid & 63;
    const int j0   = blockIdx.x * 16 + wave * 2;

    float acc0[52], acc1[52];
    #pragma unroll
    for (int r = 0; r < 52; ++r) { acc0[r] = 0.f; acc1[r] = 0.f; }

    const float* row0 = W_ih + (size_t)j0 * H;
    const float* row1 = W_ih + (size_t)(j0 + 1) * H;

    for (int c = 0; c < 16; ++c) {
        const int k0 = c * 256;
        __syncthreads();                       // previous chunk's readers done
        #pragma unroll
        for (int u = 0; u < 26; ++u) {         // 13312 / 512 = 26
            int idx = tid + u * 512;
            int r = idx >> 8, kk = idx & 255;
            xs[idx] = (r < 4) ? emb[r * H + k0 + kk]
                              : pos[(r - 4) * H + k0 + kk];
        }
        __syncthreads();

        float4 w0 = *(const float4*)(row0 + k0 + lane * 4);
        float4 w1 = *(const float4*)(row1 + k0 + lane * 4);

        #pragma unroll
        for (int r = 0; r < 52; ++r) {
            float4 x = *(const float4*)(xs + r * 256 + lane * 4);
            acc0[r] += w0.x * x.x + w0.y * x.y + w0.z * x.z + w0.w * x.w;
            acc1[r] += w1.x * x.x + w1.y * x.y + w1.z * x.z + w1.w * x.w;
        }
    }

    #pragma unroll
    for (int r = 0; r < 52; ++r) {
        float v0 = acc0[r], v1 = acc1[r];
        for (int off = 32; off; off >>= 1) {
            v0 += __shfl_xor(v0, off, 64);
            v1 += __shfl_xor(v1, off, 64);
        }
        if (lane == 0) {
            float b0 = (r >= 4) ? b_ih[j0]     : 0.f;
            float b1 = (r >= 4) ? b_ih[j0 + 1] : 0.f;
            G[(size_t)r * H3 + j0]     = v0 + b0;
            G[(size_t)r * H3 + j0 + 1] = v1 + b1;
        }
    }
}

// Fused per-step kernel A: 512 blocks x 256 thr. Block b owns i-range [b*8, b*8+8):
// computes W_hh rows {i, H+i, 2H+i} (24 rows, 6/wave), then gates + h_new + partial
// logits for its 8 i's. h double-buffered (reads h_old fully, writes its own h_new slice).
__global__ __launch_bounds__(256)
void step_matvec_kernel(const float* __restrict__ W_hh, const float* __restrict__ b_hh,
                        const float* __restrict__ G, const float* __restrict__ W_out,
                        const float* __restrict__ h_old, float* __restrict__ h_new,
                        const int* __restrict__ tok, float* __restrict__ partial,
                        int t) {
    __shared__ float4 hs4[1024];   // full h_old, 16 KB
    __shared__ float  red[24];
    const int tid = threadIdx.x;
    for (int i = tid; i < 1024; i += 256) hs4[i] = ((const float4*)h_old)[i];
    __syncthreads();

    const int wave = tid >> 6, lane = tid & 63;
    const int i0 = blockIdx.x * 8;

    #pragma unroll
    for (int m = 0; m < 6; ++m) {
        const int rr = wave * 6 + m;           // 0..23
        const int g = rr >> 3, q = rr & 7;     // gate, i-offset
        const int j = g * H + i0 + q;
        const float* row = W_hh + (size_t)j * H;
        float4 a = {0.f, 0.f, 0.f, 0.f};
        #pragma unroll
        for (int it = 0; it < 16; ++it) {
            float4 w4 = *(const float4*)(row + it * 256 + lane * 4);
            float4 x4 = hs4[it * 64 + lane];
            a.x += w4.x * x4.x; a.y += w4.y * x4.y;
            a.z += w4.z * x4.z; a.w += w4.w * x4.w;
        }
        float s = a.x + a.y + a.z + a.w;
        for (int off = 32; off; off >>= 1) s += __shfl_xor(s, off, 64);
        if (lane == 0) red[rr] = s + b_hh[j];
    }
    __syncthreads();

    if (tid < 8) {                             // lanes 0..7 of wave 0
        const int i = i0 + tid;
        const int tk = *tok;
        const float* gE = G + (size_t)tk * H3;
        const float* gP = G + (size_t)(4 + t) * H3;
        float gir = gE[i]         + gP[i];
        float giz = gE[H + i]     + gP[H + i];
        float gin = gE[2 * H + i] + gP[2 * H + i];
        float r = 1.f / (1.f + expf(-(gir + red[tid])));
        float z = 1.f / (1.f + expf(-(giz + red[8 + tid])));
        float n = tanhf(gin + r * red[16 + tid]);
        float hv = ((const float*)hs4)[i];
        float hn = (1.f - z) * n + z * hv;
        h_new[i] = hn;

        float p0 = W_out[i] * hn;
        float p1 = W_out[H + i] * hn;
        float p2 = W_out[2 * H + i] * hn;
        float p3 = W_out[3 * H + i] * hn;
        #pragma unroll
        for (int off = 4; off; off >>= 1) {    // reduce over 8 active lanes
            p0 += __shfl_xor(p0, off, 64); p1 += __shfl_xor(p1, off, 64);
            p2 += __shfl_xor(p2, off, 64); p3 += __shfl_xor(p3, off, 64);
        }
        if (tid == 0) {
            float* pb = partial + blockIdx.x * 4;
            pb[0] = p0; pb[1] = p1; pb[2] = p2; pb[3] = p3;
        }
    }
}

// Kernel B: fixed-order reduction of 512x4 partials -> argmax -> token select.
__global__ __launch_bounds__(256)
void argmax_kernel(const float* __restrict__ partial, const float* __restrict__ b_out,
                   int* __restrict__ tok, int* __restrict__ out, int t) {
    __shared__ float sum[4];
    const int tid = threadIdx.x;
    const int wave = tid >> 6, lane = tid & 63;   // wave = vocab index
    float s = 0.f;
    #pragma unroll
    for (int k = 0; k < 8; ++k) s += partial[(lane + 64 * k) * 4 + wave];
    for (int off = 32; off; off >>= 1) s += __shfl_xor(s, off, 64);
    if (lane == 0) sum[wave] = s;
    __syncthreads();
    if (tid == 0) {
        float lg[4];
        #pragma unroll
        for (int v = 0; v < 4; ++v) lg[v] = sum[v] + b_out[v];
        int best = 0;
        for (int v = 1; v < 4; ++v) if (lg[v] > lg[best]) best = v;  // first-max
        out[(t / 12) * 13 + (t % 12)] = best;
        *tok = ((t + 1) % 12 == 0) ? PAD_TOK : best;
    }
}

extern "C" void kernel_launch(void* const* d_in, const int* in_sizes, int n_in,
                              void* d_out, int out_size, void* d_ws, size_t ws_size,
                              hipStream_t stream) {
    const float* h0    = (const float*)d_in[0];
    const float* emb   = (const float*)d_in[1];
    const float* pos   = (const float*)d_in[2];
    const float* W_ih  = (const float*)d_in[3];
    const float* W_hh  = (const float*)d_in[4];
    const float* b_ih  = (const float*)d_in[5];
    const float* b_hh  = (const float*)d_in[6];
    const float* W_out = (const float*)d_in[7];
    const float* b_out = (const float*)d_in[8];

    int*   out = (int*)d_out;
    float* ws  = (float*)d_ws;
    float* G       = ws;                      // 52*12288
    float* hA      = G + 52 * H3;             // 4096
    float* hB      = hA + H;                  // 4096
    float* partial = hB + H;                  // 512*4
    int*   tok     = (int*)(partial + 512 * 4);

    hipLaunchKernelGGL(init_kernel, dim3(1), dim3(256), 0, stream, h0, hA, tok, out);
    hipLaunchKernelGGL(precompute_kernel, dim3(768), dim3(512), 0, stream,
                       emb, pos, W_ih, b_ih, G);
    for (int t = 0; t < NSTEPS; ++t) {
        const float* h_old = (t & 1) ? hB : hA;
        float*       h_new = (t & 1) ? hA : hB;
        hipLaunchKernelGGL(step_matvec_kernel, dim3(512), dim3(256), 0, stream,
                           W_hh, b_hh, G, W_out, h_old, h_new, tok, partial, t);
        hipLaunchKernelGGL(argmax_kernel, dim3(1), dim3(256), 0, stream,
                           partial, b_out, tok, out, t);
    }
}

// Round 3
// 1505.008 us; speedup vs baseline: 2.1024x; 1.2545x over previous
//
#include <hip/hip_runtime.h>
#include <hip/hip_fp16.h>
#include <cmath>

#define H     4096
#define H3    12288
#define NSTEPS 48
#define PAD_TOK 3
#define NBLK  1024   // step-kernel blocks; each owns 4 i's (12 W_hh rows)

// ---------------------------------------------------------------- init: out pads
__global__ void init_kernel(int* __restrict__ out) {
    if (threadIdx.x == 0) {
        out[12] = PAD_TOK; out[25] = PAD_TOK; out[38] = PAD_TOK; out[51] = PAD_TOK;
    }
}

// ---------------------------------------------------------------- W_hh fp32 -> fp16
__global__ __launch_bounds__(256)
void conv_kernel(const float* __restrict__ W, __half* __restrict__ W16) {
    const size_t total = (size_t)H3 * H / 8;          // 8 elems per unit
    size_t idx = (size_t)blockIdx.x * 256 + threadIdx.x;
    const size_t stride = (size_t)gridDim.x * 256;
    for (size_t u = idx; u < total; u += stride) {
        const float4* p = (const float4*)(W + u * 8);
        float4 a = p[0], b = p[1];
        float4 o;
        __half2* hp = (__half2*)&o;
        hp[0] = __floats2half2_rn(a.x, a.y);
        hp[1] = __floats2half2_rn(a.z, a.w);
        hp[2] = __floats2half2_rn(b.x, b.y);
        hp[3] = __floats2half2_rn(b.z, b.w);
        *(float4*)(W16 + u * 8) = o;                  // 16-B store
    }
}

// ---------------------------------------------------------------- precompute G
// G = X @ W_ih^T (+ b_ih on pos rows). X rows 0..3 = emb, 4..51 = pos.
// 768 blocks x 512 thr; wave owns 2 j's, all 52 rows (104 acc).
// 2-phase pipeline: double-buffered [52][128] X chunks staged via global_load_lds.
__global__ __launch_bounds__(512, 4)
void precompute_kernel(const float* __restrict__ emb, const float* __restrict__ pos,
                       const float* __restrict__ W_ih, const float* __restrict__ b_ih,
                       float* __restrict__ G) {
    __shared__ float xs[2][52 * 128];                 // 2 x 26.6 KB
    const int tid  = threadIdx.x;
    const int wave = tid >> 6;
    const int lane = tid & 63;
    const int j0   = blockIdx.x * 16 + wave * 2;

    float acc0[52], acc1[52];
    #pragma unroll
    for (int r = 0; r < 52; ++r) { acc0[r] = 0.f; acc1[r] = 0.f; }

    const float* row0 = W_ih + (size_t)j0 * H;
    const float* row1 = row0 + H;

    auto stage = [&](int c, int buf) {
        const int base = wave * 832;                  // 6656 / 8 waves
        #pragma unroll
        for (int u = 0; u < 13; ++u) {
            int e  = base + u * 64 + lane;            // elem in chunk
            int r  = e >> 7, kk = e & 127;
            const float* src = (r < 4) ? (emb + (size_t)r * H + c * 128 + kk)
                                       : (pos + (size_t)(r - 4) * H + c * 128 + kk);
            __builtin_amdgcn_global_load_lds(
                (const __attribute__((address_space(1))) void*)src,
                (__attribute__((address_space(3))) void*)&xs[buf][base + u * 64],
                4, 0, 0);
        }
    };

    stage(0, 0);
    __syncthreads();                                  // drains vmcnt + barrier

    for (int c = 0; c < 32; ++c) {
        const int buf = c & 1;
        if (c < 31) stage(c + 1, buf ^ 1);            // async, flies under compute
        float2 w0 = *(const float2*)(row0 + c * 128 + lane * 2);
        float2 w1 = *(const float2*)(row1 + c * 128 + lane * 2);
        #pragma unroll
        for (int r = 0; r < 52; ++r) {
            float2 x = *(const float2*)&xs[buf][r * 128 + lane * 2];
            acc0[r] += w0.x * x.x + w0.y * x.y;
            acc1[r] += w1.x * x.x + w1.y * x.y;
        }
        __syncthreads();                              // one barrier per chunk
    }

    const float bj0 = b_ih[j0], bj1 = b_ih[j0 + 1];
    #pragma unroll
    for (int r = 0; r < 52; ++r) {
        float v0 = acc0[r], v1 = acc1[r];
        for (int off = 32; off; off >>= 1) {
            v0 += __shfl_xor(v0, off, 64);
            v1 += __shfl_xor(v1, off, 64);
        }
        if (lane == 0) {
            G[(size_t)r * H3 + j0]     = v0 + (r >= 4 ? bj0 : 0.f);
            G[(size_t)r * H3 + j0 + 1] = v1 + (r >= 4 ? bj1 : 0.f);
        }
    }
}

// ---------------------------------------------------------------- fused step
// Block b owns i in [4b, 4b+4). Start: all blocks redundantly reduce prev partials
// -> tok (block 0 writes out[t-1]). Then 12-row matvec (3 rows/wave, h from global/L1),
// gates, h_new, per-block partial logits.
template <typename WT>
__global__ __launch_bounds__(256, 4)
void step_kernel(const WT* __restrict__ Wh, const float* __restrict__ b_hh,
                 const float* __restrict__ G, const float* __restrict__ W_out,
                 const float* __restrict__ b_out,
                 const float* __restrict__ h_old, float* __restrict__ h_new,
                 float* __restrict__ partial, int* __restrict__ out, int t) {
    __shared__ float red[12];
    __shared__ float sums[4];
    __shared__ int   tok_s;
    const int tid = threadIdx.x, wave = tid >> 6, lane = tid & 63;

    if (t == 0) {
        if (tid == 0) tok_s = PAD_TOK;
    } else {
        float s = 0.f;                                 // wave = vocab index
        #pragma unroll
        for (int m = 0; m < NBLK / 64; ++m) s += partial[(lane + 64 * m) * 4 + wave];
        for (int off = 32; off; off >>= 1) s += __shfl_xor(s, off, 64);
        if (lane == 0) sums[wave] = s;
        __syncthreads();
        if (tid == 0) {
            float lg[4]; int best = 0;
            #pragma unroll
            for (int v = 0; v < 4; ++v) lg[v] = sums[v] + b_out[v];
            for (int v = 1; v < 4; ++v) if (lg[v] > lg[best]) best = v;  // first-max
            tok_s = (t % 12 == 0) ? PAD_TOK : best;
            if (blockIdx.x == 0)
                out[((t - 1) / 12) * 13 + ((t - 1) % 12)] = best;
        }
    }

    // ---- matvec: rows rr = wave*3 + {0,1,2}; rr -> g = rr>>2, q = rr&3
    const int i0 = blockIdx.x * 4;
    float acc[3] = {0.f, 0.f, 0.f};
    int jm[3];
    const WT* rp[3];
    #pragma unroll
    for (int m = 0; m < 3; ++m) {
        int rr = wave * 3 + m;
        jm[m] = (rr >> 2) * H + i0 + (rr & 3);
        rp[m] = Wh + (size_t)jm[m] * H;
    }

    if constexpr (sizeof(WT) == 2) {                   // fp16 weights
        #pragma unroll 4
        for (int it = 0; it < 8; ++it) {
            const int kb = it * 512 + lane * 8;
            float4 xa = *(const float4*)(h_old + kb);
            float4 xb = *(const float4*)(h_old + kb + 4);
            #pragma unroll
            for (int m = 0; m < 3; ++m) {
                float4 wv = *(const float4*)(rp[m] + kb);   // 8 halves
                const __half2* hp = (const __half2*)&wv;
                float2 f0 = __half22float2(hp[0]);
                float2 f1 = __half22float2(hp[1]);
                float2 f2 = __half22float2(hp[2]);
                float2 f3 = __half22float2(hp[3]);
                acc[m] += f0.x * xa.x + f0.y * xa.y + f1.x * xa.z + f1.y * xa.w
                        + f2.x * xb.x + f2.y * xb.y + f3.x * xb.z + f3.y * xb.w;
            }
        }
    } else {                                           // fp32 fallback
        #pragma unroll 4
        for (int it = 0; it < 16; ++it) {
            const int kb = it * 256 + lane * 4;
            float4 x = *(const float4*)(h_old + kb);
            #pragma unroll
            for (int m = 0; m < 3; ++m) {
                float4 w = *(const float4*)((const float*)rp[m] + kb);
                acc[m] += w.x * x.x + w.y * x.y + w.z * x.z + w.w * x.w;
            }
        }
    }

    #pragma unroll
    for (int m = 0; m < 3; ++m) {
        float s = acc[m];
        for (int off = 32; off; off >>= 1) s += __shfl_xor(s, off, 64);
        if (lane == 0) red[wave * 3 + m] = s + b_hh[jm[m]];
    }
    __syncthreads();

    if (tid < 4) {
        const int i = i0 + tid;
        const int tk = tok_s;
        const float* gE = G + (size_t)tk * H3;
        const float* gP = G + (size_t)(4 + t) * H3;
        float gir = gE[i]         + gP[i];
        float giz = gE[H + i]     + gP[H + i];
        float gin = gE[2 * H + i] + gP[2 * H + i];
        float r = 1.f / (1.f + expf(-(gir + red[tid])));
        float z = 1.f / (1.f + expf(-(giz + red[4 + tid])));
        float n = tanhf(gin + r * red[8 + tid]);
        float hn = (1.f - z) * n + z * h_old[i];
        h_new[i] = hn;

        float p0 = W_out[i] * hn;
        float p1 = W_out[H + i] * hn;
        float p2 = W_out[2 * H + i] * hn;
        float p3 = W_out[3 * H + i] * hn;
        #pragma unroll
        for (int off = 2; off; off >>= 1) {
            p0 += __shfl_xor(p0, off, 64); p1 += __shfl_xor(p1, off, 64);
            p2 += __shfl_xor(p2, off, 64); p3 += __shfl_xor(p3, off, 64);
        }
        if (tid == 0) {
            float* pb = partial + (size_t)blockIdx.x * 4;
            pb[0] = p0; pb[1] = p1; pb[2] = p2; pb[3] = p3;
        }
    }
}

// ---------------------------------------------------------------- final argmax (t=47)
__global__ __launch_bounds__(256)
void final_kernel(const float* __restrict__ partial, const float* __restrict__ b_out,
                  int* __restrict__ out) {
    __shared__ float sums[4];
    const int tid = threadIdx.x, wave = tid >> 6, lane = tid & 63;
    float s = 0.f;
    #pragma unroll
    for (int m = 0; m < NBLK / 64; ++m) s += partial[(lane + 64 * m) * 4 + wave];
    for (int off = 32; off; off >>= 1) s += __shfl_xor(s, off, 64);
    if (lane == 0) sums[wave] = s;
    __syncthreads();
    if (tid == 0) {
        float lg[4]; int best = 0;
        #pragma unroll
        for (int v = 0; v < 4; ++v) lg[v] = sums[v] + b_out[v];
        for (int v = 1; v < 4; ++v) if (lg[v] > lg[best]) best = v;
        out[(47 / 12) * 13 + (47 % 12)] = best;        // out[50]
    }
}

// ---------------------------------------------------------------- launch
extern "C" void kernel_launch(void* const* d_in, const int* in_sizes, int n_in,
                              void* d_out, int out_size, void* d_ws, size_t ws_size,
                              hipStream_t stream) {
    const float* ts    = (const float*)d_in[0];
    const float* emb   = (const float*)d_in[1];
    const float* pos   = (const float*)d_in[2];
    const float* W_ih  = (const float*)d_in[3];
    const float* W_hh  = (const float*)d_in[4];
    const float* b_ih  = (const float*)d_in[5];
    const float* b_hh  = (const float*)d_in[6];
    const float* W_out = (const float*)d_in[7];
    const float* b_out = (const float*)d_in[8];
    int* out = (int*)d_out;

    const size_t w16_bytes = (size_t)H3 * H * 2;               // 100.7 MB
    const size_t rest_bytes = (size_t)52 * H3 * 4 + 2 * H * 4 + NBLK * 4 * 4;
    const bool f16 = ws_size >= w16_bytes + rest_bytes + 256;

    char* wp = (char*)d_ws;
    __half* W16 = nullptr;
    if (f16) { W16 = (__half*)wp; wp += w16_bytes; }
    float* G       = (float*)wp;  wp += (size_t)52 * H3 * 4;
    float* hA      = (float*)wp;  wp += H * 4;
    float* hB      = (float*)wp;  wp += H * 4;
    float* partial = (float*)wp;

    hipLaunchKernelGGL(init_kernel, dim3(1), dim3(64), 0, stream, out);
    if (f16)
        hipLaunchKernelGGL(conv_kernel, dim3(4096), dim3(256), 0, stream, W_hh, W16);
    hipLaunchKernelGGL(precompute_kernel, dim3(768), dim3(512), 0, stream,
                       emb, pos, W_ih, b_ih, G);

    for (int t = 0; t < NSTEPS; ++t) {
        const float* ho = (t == 0) ? ts : ((t & 1) ? hA : hB);
        float*       hn = (t & 1) ? hB : hA;
        if (f16)
            hipLaunchKernelGGL(step_kernel<__half>, dim3(NBLK), dim3(256), 0, stream,
                               W16, b_hh, G, W_out, b_out, ho, hn, partial, out, t);
        else
            hipLaunchKernelGGL(step_kernel<float>, dim3(NBLK), dim3(256), 0, stream,
                               W_hh, b_hh, G, W_out, b_out, ho, hn, partial, out, t);
    }
    hipLaunchKernelGGL(final_kernel, dim3(1), dim3(256), 0, stream,
                       partial, b_out, out);
}

// Round 4
// 1298.251 us; speedup vs baseline: 2.4373x; 1.1593x over previous
//
#include <hip/hip_runtime.h>
#include <hip/hip_fp16.h>
#include <cmath>

#define H     4096
#define H3    12288
#define NSTEPS 48
#define PAD_TOK 3
#define NBLK  1024   // step-kernel blocks; each owns 4 i's (12 W_hh rows)

// ---------------------------------------------------------------- init: out pads
__global__ void init_kernel(int* __restrict__ out) {
    if (threadIdx.x == 0) {
        out[12] = PAD_TOK; out[25] = PAD_TOK; out[38] = PAD_TOK; out[51] = PAD_TOK;
    }
}

// ---------------------------------------------------------------- W_hh fp32 -> fp16
__global__ __launch_bounds__(256)
void conv_kernel(const float* __restrict__ W, __half* __restrict__ W16) {
    const size_t total = (size_t)H3 * H / 8;
    size_t idx = (size_t)blockIdx.x * 256 + threadIdx.x;
    const size_t stride = (size_t)gridDim.x * 256;
    for (size_t u = idx; u < total; u += stride) {
        const float4* p = (const float4*)(W + u * 8);
        float4 a = p[0], b = p[1];
        float4 o;
        __half2* hp = (__half2*)&o;
        hp[0] = __floats2half2_rn(a.x, a.y);
        hp[1] = __floats2half2_rn(a.z, a.w);
        hp[2] = __floats2half2_rn(b.x, b.y);
        hp[3] = __floats2half2_rn(b.z, b.w);
        *(float4*)(W16 + u * 8) = o;
    }
}

// ---------------------------------------------------------------- precompute G
// G = X @ W_ih^T (+ b_ih on pos rows). X rows 0..3 = emb, 4..51 = pos.
// 768 blocks x 512 thr; wave owns 2 j's, all 52 rows (104 accs).
// Double-buffered [52][128] X chunks via global_load_lds + W prefetched 1 chunk
// ahead into registers. launch_bounds(512,2): 256-VGPR cap — 104 accs must NOT
// spill (r1/r3 regressions were both VGPR-cap spills: 4.5GB / 190MB scratch).
__global__ __launch_bounds__(512, 2)
void precompute_kernel(const float* __restrict__ emb, const float* __restrict__ pos,
                       const float* __restrict__ W_ih, const float* __restrict__ b_ih,
                       float* __restrict__ G) {
    __shared__ float xs[2][52 * 128];                 // 2 x 26.6 KB
    const int tid  = threadIdx.x;
    const int wave = tid >> 6;
    const int lane = tid & 63;
    const int j0   = blockIdx.x * 16 + wave * 2;

    float acc0[52], acc1[52];
    #pragma unroll
    for (int r = 0; r < 52; ++r) { acc0[r] = 0.f; acc1[r] = 0.f; }

    const float* row0 = W_ih + (size_t)j0 * H;
    const float* row1 = row0 + H;

    auto stage = [&](int c, int buf) {
        const int base = wave * 832;                  // 6656 / 8 waves
        #pragma unroll
        for (int u = 0; u < 13; ++u) {
            int e  = base + u * 64 + lane;
            int r  = e >> 7, kk = e & 127;            // uniform r per 64-group
            const float* src = (r < 4) ? (emb + (size_t)r * H + c * 128 + kk)
                                       : (pos + (size_t)(r - 4) * H + c * 128 + kk);
            __builtin_amdgcn_global_load_lds(
                (const __attribute__((address_space(1))) void*)src,
                (__attribute__((address_space(3))) void*)&xs[buf][base + u * 64],
                4, 0, 0);
        }
    };

    stage(0, 0);
    float2 w0n = *(const float2*)(row0 + lane * 2);   // W prefetch, chunk 0
    float2 w1n = *(const float2*)(row1 + lane * 2);
    __syncthreads();                                  // drains vmcnt + barrier

    for (int c = 0; c < 32; ++c) {
        const int buf = c & 1;
        float2 w0 = w0n, w1 = w1n;
        if (c < 31) {
            stage(c + 1, buf ^ 1);                    // async into other buffer
            w0n = *(const float2*)(row0 + (c + 1) * 128 + lane * 2);
            w1n = *(const float2*)(row1 + (c + 1) * 128 + lane * 2);
        }
        #pragma unroll
        for (int r = 0; r < 52; ++r) {
            float2 x = *(const float2*)&xs[buf][r * 128 + lane * 2];
            acc0[r] += w0.x * x.x + w0.y * x.y;
            acc1[r] += w1.x * x.x + w1.y * x.y;
        }
        __syncthreads();                              // one barrier per chunk
    }

    const float bj0 = b_ih[j0], bj1 = b_ih[j0 + 1];
    #pragma unroll
    for (int r = 0; r < 52; ++r) {
        float v0 = acc0[r], v1 = acc1[r];
        for (int off = 32; off; off >>= 1) {
            v0 += __shfl_xor(v0, off, 64);
            v1 += __shfl_xor(v1, off, 64);
        }
        if (lane == 0) {
            G[(size_t)r * H3 + j0]     = v0 + (r >= 4 ? bj0 : 0.f);
            G[(size_t)r * H3 + j0 + 1] = v1 + (r >= 4 ? bj1 : 0.f);
        }
    }
}

// ---------------------------------------------------------------- fused step
// Order: (1) 12-row W_hh matvec (the memory-heavy part issues first),
// (2) per-wave REDUNDANT argmax of prev partials (hides under matvec drain,
// no extra barrier), (3) single barrier, (4) gates + h_new + new partials.
// partial is parity double-buffered (part_in/part_out) — same-launch
// read/write race otherwise.
template <typename WT>
__global__ __launch_bounds__(256)
void step_kernel(const WT* __restrict__ Wh, const float* __restrict__ b_hh,
                 const float* __restrict__ G, const float* __restrict__ W_out,
                 const float* __restrict__ b_out,
                 const float* __restrict__ h_old, float* __restrict__ h_new,
                 const float* __restrict__ part_in, float* __restrict__ part_out,
                 int* __restrict__ out, int t) {
    __shared__ float red[12];
    const int tid = threadIdx.x, wave = tid >> 6, lane = tid & 63;
    const int i0 = blockIdx.x * 4;

    // ---- matvec: rows rr = wave*3 + {0,1,2}; rr -> gate = rr>>2, i-off = rr&3
    float acc[3] = {0.f, 0.f, 0.f};
    int jm[3];
    const WT* rp[3];
    #pragma unroll
    for (int m = 0; m < 3; ++m) {
        int rr = wave * 3 + m;
        jm[m] = (rr >> 2) * H + i0 + (rr & 3);
        rp[m] = Wh + (size_t)jm[m] * H;
    }

    if constexpr (sizeof(WT) == 2) {                   // fp16 weights
        #pragma unroll 4
        for (int it = 0; it < 8; ++it) {
            const int kb = it * 512 + lane * 8;
            float4 xa = *(const float4*)(h_old + kb);
            float4 xb = *(const float4*)(h_old + kb + 4);
            #pragma unroll
            for (int m = 0; m < 3; ++m) {
                float4 wv = *(const float4*)(rp[m] + kb);   // 8 halves
                const __half2* hp = (const __half2*)&wv;
                float2 f0 = __half22float2(hp[0]);
                float2 f1 = __half22float2(hp[1]);
                float2 f2 = __half22float2(hp[2]);
                float2 f3 = __half22float2(hp[3]);
                acc[m] += f0.x * xa.x + f0.y * xa.y + f1.x * xa.z + f1.y * xa.w
                        + f2.x * xb.x + f2.y * xb.y + f3.x * xb.z + f3.y * xb.w;
            }
        }
    } else {                                           // fp32 fallback
        #pragma unroll 4
        for (int it = 0; it < 16; ++it) {
            const int kb = it * 256 + lane * 4;
            float4 x = *(const float4*)(h_old + kb);
            #pragma unroll
            for (int m = 0; m < 3; ++m) {
                float4 w = *(const float4*)((const float*)rp[m] + kb);
                acc[m] += w.x * x.x + w.y * x.y + w.z * x.z + w.w * x.w;
            }
        }
    }

    #pragma unroll
    for (int m = 0; m < 3; ++m) {
        float s = acc[m];
        for (int off = 32; off; off >>= 1) s += __shfl_xor(s, off, 64);
        if (lane == 0) red[wave * 3 + m] = s + b_hh[jm[m]];
    }

    // ---- redundant per-wave argmax (identical order in every wave -> identical tok)
    int tok = PAD_TOK;
    if (t > 0) {
        float4 p = {0.f, 0.f, 0.f, 0.f};
        #pragma unroll
        for (int m = 0; m < NBLK / 64; ++m) {
            float4 q = ((const float4*)part_in)[lane + 64 * m];
            p.x += q.x; p.y += q.y; p.z += q.z; p.w += q.w;
        }
        #pragma unroll
        for (int off = 32; off; off >>= 1) {
            p.x += __shfl_xor(p.x, off, 64);
            p.y += __shfl_xor(p.y, off, 64);
            p.z += __shfl_xor(p.z, off, 64);
            p.w += __shfl_xor(p.w, off, 64);
        }
        float lg[4] = {p.x + b_out[0], p.y + b_out[1], p.z + b_out[2], p.w + b_out[3]};
        int best = 0;
        #pragma unroll
        for (int v = 1; v < 4; ++v) if (lg[v] > lg[best]) best = v;  // first-max
        if (blockIdx.x == 0 && tid == 0)
            out[((t - 1) / 12) * 13 + ((t - 1) % 12)] = best;
        tok = (t % 12 == 0) ? PAD_TOK : best;
    }
    __syncthreads();                                   // red[] ready

    if (tid < 4) {                                     // wave 0: tok valid here
        const int i = i0 + tid;
        const float* gE = G + (size_t)tok * H3;
        const float* gP = G + (size_t)(4 + t) * H3;
        float gir = gE[i]         + gP[i];
        float giz = gE[H + i]     + gP[H + i];
        float gin = gE[2 * H + i] + gP[2 * H + i];
        float r = 1.f / (1.f + expf(-(gir + red[tid])));
        float z = 1.f / (1.f + expf(-(giz + red[4 + tid])));
        float n = tanhf(gin + r * red[8 + tid]);
        float hn = (1.f - z) * n + z * h_old[i];
        h_new[i] = hn;

        float p0 = W_out[i] * hn;
        float p1 = W_out[H + i] * hn;
        float p2 = W_out[2 * H + i] * hn;
        float p3 = W_out[3 * H + i] * hn;
        #pragma unroll
        for (int off = 2; off; off >>= 1) {
            p0 += __shfl_xor(p0, off, 64); p1 += __shfl_xor(p1, off, 64);
            p2 += __shfl_xor(p2, off, 64); p3 += __shfl_xor(p3, off, 64);
        }
        if (tid == 0) {
            float* pb = part_out + (size_t)blockIdx.x * 4;
            pb[0] = p0; pb[1] = p1; pb[2] = p2; pb[3] = p3;
        }
    }
}

// ---------------------------------------------------------------- final argmax (t=47)
__global__ __launch_bounds__(256)
void final_kernel(const float* __restrict__ partial, const float* __restrict__ b_out,
                  int* __restrict__ out) {
    __shared__ float sums[4];
    const int tid = threadIdx.x, wave = tid >> 6, lane = tid & 63;
    float s = 0.f;
    #pragma unroll
    for (int m = 0; m < NBLK / 64; ++m) s += partial[(lane + 64 * m) * 4 + wave];
    for (int off = 32; off; off >>= 1) s += __shfl_xor(s, off, 64);
    if (lane == 0) sums[wave] = s;
    __syncthreads();
    if (tid == 0) {
        float lg[4]; int best = 0;
        #pragma unroll
        for (int v = 0; v < 4; ++v) lg[v] = sums[v] + b_out[v];
        for (int v = 1; v < 4; ++v) if (lg[v] > lg[best]) best = v;
        out[(47 / 12) * 13 + (47 % 12)] = best;        // out[50]
    }
}

// ---------------------------------------------------------------- launch
extern "C" void kernel_launch(void* const* d_in, const int* in_sizes, int n_in,
                              void* d_out, int out_size, void* d_ws, size_t ws_size,
                              hipStream_t stream) {
    const float* ts    = (const float*)d_in[0];
    const float* emb   = (const float*)d_in[1];
    const float* pos   = (const float*)d_in[2];
    const float* W_ih  = (const float*)d_in[3];
    const float* W_hh  = (const float*)d_in[4];
    const float* b_ih  = (const float*)d_in[5];
    const float* b_hh  = (const float*)d_in[6];
    const float* W_out = (const float*)d_in[7];
    const float* b_out = (const float*)d_in[8];
    int* out = (int*)d_out;

    const size_t w16_bytes  = (size_t)H3 * H * 2;              // 100.7 MB
    const size_t rest_bytes = (size_t)52 * H3 * 4 + 2 * H * 4 + 2 * NBLK * 4 * 4;
    const bool f16 = ws_size >= w16_bytes + rest_bytes + 256;

    char* wp = (char*)d_ws;
    __half* W16 = nullptr;
    if (f16) { W16 = (__half*)wp; wp += w16_bytes; }
    float* G  = (float*)wp;  wp += (size_t)52 * H3 * 4;
    float* hA = (float*)wp;  wp += H * 4;
    float* hB = (float*)wp;  wp += H * 4;
    float* P0 = (float*)wp;  wp += NBLK * 4 * 4;
    float* P1 = (float*)wp;

    hipLaunchKernelGGL(init_kernel, dim3(1), dim3(64), 0, stream, out);
    if (f16)
        hipLaunchKernelGGL(conv_kernel, dim3(4096), dim3(256), 0, stream, W_hh, W16);
    hipLaunchKernelGGL(precompute_kernel, dim3(768), dim3(512), 0, stream,
                       emb, pos, W_ih, b_ih, G);

    for (int t = 0; t < NSTEPS; ++t) {
        const float* ho = (t == 0) ? ts : ((t & 1) ? hA : hB);
        float*       hn = (t & 1) ? hB : hA;
        float* po = (t & 1) ? P1 : P0;                 // write buffer, parity t
        float* pi = (t & 1) ? P0 : P1;                 // read buffer, parity t-1
        if (f16)
            hipLaunchKernelGGL(step_kernel<__half>, dim3(NBLK), dim3(256), 0, stream,
                               W16, b_hh, G, W_out, b_out, ho, hn, pi, po, out, t);
        else
            hipLaunchKernelGGL(step_kernel<float>, dim3(NBLK), dim3(256), 0, stream,
                               W_hh, b_hh, G, W_out, b_out, ho, hn, pi, po, out, t);
    }
    hipLaunchKernelGGL(final_kernel, dim3(1), dim3(256), 0, stream,
                       P1, b_out, out);                // t=47 wrote parity-1 buffer
}